// Round 7
// baseline (522.947 us; speedup 1.0000x reference)
//
#include <hip/hip_runtime.h>
#include <hip/hip_cooperative_groups.h>
#include <math.h>

namespace cg = cooperative_groups;

#define NROWS 8192
#define DDIM  512
#define NTRIP 200000
#define CHUNK 16                  // triplets per work unit (balance quantum)
#define MAXCH 4                   // chunks per bin
#define BINCAP (CHUNK * MAXCH)    // 64
#define NCHUNKS (NROWS * MAXCH)   // 32768

typedef __attribute__((ext_vector_type(8))) _Float16 half8;
typedef __attribute__((ext_vector_type(4))) _Float16 half4;
typedef __attribute__((ext_vector_type(2))) _Float16 half2v;

__device__ __forceinline__ float wave_sum_all(float v) {
    #pragma unroll
    for (int off = 32; off > 0; off >>= 1) v += __shfl_xor(v, off, 64);
    return v;
}

__device__ __forceinline__ float dot8(const half8 a, const half8 b, float acc) {
#if __has_builtin(__builtin_amdgcn_fdot2)
    acc = __builtin_amdgcn_fdot2((half2v){a[0],a[1]}, (half2v){b[0],b[1]}, acc, false);
    acc = __builtin_amdgcn_fdot2((half2v){a[2],a[3]}, (half2v){b[2],b[3]}, acc, false);
    acc = __builtin_amdgcn_fdot2((half2v){a[4],a[5]}, (half2v){b[4],b[5]}, acc, false);
    acc = __builtin_amdgcn_fdot2((half2v){a[6],a[7]}, (half2v){b[6],b[7]}, acc, false);
    return acc;
#else
    #pragma unroll
    for (int e = 0; e < 8; ++e) acc += (float)a[e] * (float)b[e];
    return acc;
#endif
}

// softplus(z) = max(z,0) + log1p(exp(-|z|)), hardware exp/log.
__device__ __forceinline__ float softplus_fast(float z) {
    return fmaxf(z, 0.0f) + __logf(1.0f + __expf(-fabsf(z)));
}

// ONE persistent cooperative kernel: scatter+prep | sync | trip | sync | reduce.
__global__ __launch_bounds__(256, 6) void fused_kernel(
    const float* __restrict__ x, const float* __restrict__ y,
    const float* __restrict__ norm_s, const int* __restrict__ trip,
    int* __restrict__ count, int2* __restrict__ slots,
    _Float16* __restrict__ xh, _Float16* __restrict__ yh,
    float2* __restrict__ sq, float* __restrict__ bpart,
    float* __restrict__ out)
{
    cg::grid_group grid = cg::this_grid();
    const int tid      = threadIdx.x;
    const int lane     = tid & 63;
    const int wv       = tid >> 6;
    const int nblocks  = gridDim.x;
    const int gthreads = nblocks * 256;
    const int nwaves   = nblocks * 4;

    // ================= Phase A: triplet scatter (count pre-zeroed) ==========
    for (int t = blockIdx.x * 256 + tid; t < NTRIP; t += gthreads) {
        const int i = trip[3*t], j = trip[3*t+1], k = trip[3*t+2];
        const int c = atomicAdd(&count[i], 1);   // 200k atomics over 8192 addrs
        if (c < BINCAP) slots[((size_t)i << 6) + c] = (int2){j, k};
    }

    // ================= Phase A: row prep (one wave per row) =================
    for (int row = blockIdx.x * 4 + wv; row < NROWS; row += nwaves) {
        const float4* xr = (const float4*)(x + (size_t)row * DDIM);
        const float4* yr = (const float4*)(y + (size_t)row * DDIM);
        const float4 x0 = xr[lane], x1 = xr[lane + 64];
        const float4 y0 = yr[lane], y1 = yr[lane + 64];

        float sy = y0.x*y0.x + y0.y*y0.y + y0.z*y0.z + y0.w*y0.w
                 + y1.x*y1.x + y1.y*y1.y + y1.z*y1.z + y1.w*y1.w;
        sy = wave_sum_all(sy);
        const float scale = norm_s[0] / sqrtf(sy);

        const half4 hx0 = {(_Float16)x0.x, (_Float16)x0.y, (_Float16)x0.z, (_Float16)x0.w};
        const half4 hx1 = {(_Float16)x1.x, (_Float16)x1.y, (_Float16)x1.z, (_Float16)x1.w};
        const half4 hy0 = {(_Float16)(y0.x*scale), (_Float16)(y0.y*scale),
                           (_Float16)(y0.z*scale), (_Float16)(y0.w*scale)};
        const half4 hy1 = {(_Float16)(y1.x*scale), (_Float16)(y1.y*scale),
                           (_Float16)(y1.z*scale), (_Float16)(y1.w*scale)};

        // sq-norms of the ROUNDED values so i==j distances cancel pre-clamp
        float sx = 0.f, sqy = 0.f;
        #pragma unroll
        for (int e = 0; e < 4; ++e) {
            sx  += (float)hx0[e]*(float)hx0[e] + (float)hx1[e]*(float)hx1[e];
            sqy += (float)hy0[e]*(float)hy0[e] + (float)hy1[e]*(float)hy1[e];
        }
        sx  = wave_sum_all(sx);
        sqy = wave_sum_all(sqy);

        ((half4*)(xh + (size_t)row * DDIM))[lane]      = hx0;
        ((half4*)(xh + (size_t)row * DDIM))[lane + 64] = hx1;
        ((half4*)(yh + (size_t)row * DDIM))[lane]      = hy0;
        ((half4*)(yh + (size_t)row * DDIM))[lane + 64] = hy1;
        if (lane == 0) sq[row] = (float2){sx, sqy};
    }

    grid.sync();

    // ================= Phase B: triplet chunks ==============================
    // 4 groups of 16 lanes: g0:x_j g1:x_k g2:y_j g3:y_k. All 4 dots of a
    // triplet reduce in one 4-level butterfly; transposed epilogue.
    const int  s     = lane & 15;
    const bool isK   = (lane & 16) != 0;
    const bool isTxt = (lane & 32) != 0;
    const _Float16* base = isTxt ? yh : xh;

    float acc = 0.0f;
    for (int chunk = blockIdx.x * 4 + wv; chunk < NCHUNKS; chunk += nwaves) {
        const int c   = chunk >> 13;          // chunk-major
        const int bin = chunk & (NROWS - 1);  // == i

        int n = count[bin];
        n = __builtin_amdgcn_readfirstlane(n < BINCAP ? n : BINCAP);
        int m = n - c * CHUNK;
        if (m <= 0) continue;
        if (m > CHUNK) m = CHUNK;

        const half8* irow = ((const half8*)(base + (size_t)bin * DDIM)) + (s << 2);
        const half8 ci0 = irow[0], ci1 = irow[1], ci2 = irow[2], ci3 = irow[3];
        const float2 sqi = sq[bin];
        const float sq_self = isTxt ? sqi.y : sqi.x;
        const int2* bs = slots + ((size_t)bin << 6) + c * CHUNK;

        int t = 0;
        for (; t + 4 <= m; t += 4) {
            int jj[4], kk[4];
            #pragma unroll
            for (int u = 0; u < 4; ++u) {
                const int2 p = bs[t + u];
                jj[u] = __builtin_amdgcn_readfirstlane(p.x);
                kk[u] = __builtin_amdgcn_readfirstlane(p.y);
            }
            half8 rv[4][4];
            #pragma unroll
            for (int u = 0; u < 4; ++u) {
                const int r = isK ? kk[u] : jj[u];
                const half8* rp = ((const half8*)(base + (size_t)r * DDIM)) + (s << 2);
                rv[u][0] = rp[0]; rv[u][1] = rp[1]; rv[u][2] = rp[2]; rv[u][3] = rp[3];
            }
            float sq_r[4];
            #pragma unroll
            for (int u = 0; u < 4; ++u) {
                const float2 sqj = sq[jj[u]];
                const float2 sqk = sq[kk[u]];
                sq_r[u] = isTxt ? (isK ? sqk.y : sqj.y) : (isK ? sqk.x : sqj.x);
            }
            float dist[4];
            #pragma unroll
            for (int u = 0; u < 4; ++u) {
                float p = dot8(ci0, rv[u][0], 0.0f);
                p = dot8(ci1, rv[u][1], p);
                p = dot8(ci2, rv[u][2], p);
                p = dot8(ci3, rv[u][3], p);
                #pragma unroll
                for (int off = 1; off < 16; off <<= 1) p += __shfl_xor(p, off, 64);
                dist[u] = fmaxf(sq_self + sq_r[u] - 2.0f * p, 0.0f);
            }
            #pragma unroll
            for (int u = 0; u < 4; ++u) {
                const float z = dist[u] - __shfl_xor(dist[u], 16, 64);
                acc += isK ? 0.0f : softplus_fast(z);  // groups 0 (img), 2 (txt)
            }
        }
        for (; t < m; ++t) {  // tail, <=3 iterations
            const int2 p0 = bs[t];
            const int j0 = __builtin_amdgcn_readfirstlane(p0.x);
            const int k0 = __builtin_amdgcn_readfirstlane(p0.y);
            const int r = isK ? k0 : j0;
            const half8* rp = ((const half8*)(base + (size_t)r * DDIM)) + (s << 2);
            float p = dot8(ci0, rp[0], 0.0f);
            p = dot8(ci1, rp[1], p);
            p = dot8(ci2, rp[2], p);
            p = dot8(ci3, rp[3], p);
            #pragma unroll
            for (int off = 1; off < 16; off <<= 1) p += __shfl_xor(p, off, 64);
            const float2 sqj = sq[j0];
            const float2 sqk = sq[k0];
            const float sq_r = isTxt ? (isK ? sqk.y : sqj.y) : (isK ? sqk.x : sqj.x);
            const float dist = fmaxf(sq_self + sq_r - 2.0f * p, 0.0f);
            const float z = dist - __shfl_xor(dist, 16, 64);
            acc += isK ? 0.0f : softplus_fast(z);
        }
    }

    // block partial: every block writes its slot (no zeroing, no atomics)
    acc = wave_sum_all(acc);
    __shared__ float red[4];
    if (lane == 0) red[wv] = acc;
    __syncthreads();
    if (tid == 0) bpart[blockIdx.x] = red[0] + red[1] + red[2] + red[3];

    grid.sync();

    // ================= Phase C: final reduce by block 0 =====================
    if (blockIdx.x == 0) {
        float sacc = 0.0f;
        for (int b = tid; b < nblocks; b += 256) sacc += bpart[b];
        sacc = wave_sum_all(sacc);
        __shared__ float red2[4];
        if (lane == 0) red2[wv] = sacc;
        __syncthreads();
        if (tid == 0)
            out[0] = (red2[0] + red2[1] + red2[2] + red2[3])
                     * (1.0f / (16.0f * (float)NTRIP));
    }
}

extern "C" void kernel_launch(void* const* d_in, const int* in_sizes, int n_in,
                              void* d_out, int out_size, void* d_ws, size_t ws_size,
                              hipStream_t stream) {
    const float* x      = (const float*)d_in[0];
    const float* y      = (const float*)d_in[1];
    const float* norm_s = (const float*)d_in[2];
    const int*   trip   = (const int*)d_in[3];

    _Float16* xh    = (_Float16*)d_ws;                          // 8 MB
    _Float16* yh    = xh + (size_t)NROWS * DDIM;                // 8 MB
    float2*   sq    = (float2*)(yh + (size_t)NROWS * DDIM);     // 64 KB
    int*      count = (int*)(sq + NROWS);                       // 32 KB
    float*    bpart = (float*)(count + NROWS);                  // 16 KB
    int2*     slots = (int2*)(bpart + 4096);                    // 4 MB

    // grid = max co-resident blocks (cooperative launch requirement)
    int per_cu = 0;
    (void)hipOccupancyMaxActiveBlocksPerMultiprocessor(&per_cu, fused_kernel, 256, 0);
    if (per_cu < 1) per_cu = 1;
    if (per_cu > 8) per_cu = 8;
    int blocks = per_cu * 256;           // 256 CUs on MI355X
    if (blocks > 4096) blocks = 4096;

    hipMemsetAsync(count, 0, sizeof(int) * NROWS, stream);

    void* args[] = {(void*)&x, (void*)&y, (void*)&norm_s, (void*)&trip,
                    (void*)&count, (void*)&slots, (void*)&xh, (void*)&yh,
                    (void*)&sq, (void*)&bpart, (void*)&d_out};
    (void)hipLaunchCooperativeKernel((const void*)fused_kernel, dim3(blocks),
                                     dim3(256), args, 0, stream);
}

// Round 8
// 239.394 us; speedup vs baseline: 2.1845x; 2.1845x over previous
//
#include <hip/hip_runtime.h>
#include <math.h>

#define NROWS 8192
#define DDIM  512
#define NTRIP 200000
#define CHUNK 16                  // triplets per work unit (balance quantum)
#define MAXCH 4                   // chunks per bin
#define BINCAP (CHUNK * MAXCH)    // 64
#define NCHUNKS (NROWS * MAXCH)   // 32768
#define TBLOCKS 1024              // trip grid (4 blocks/CU, grid-stride)

typedef __attribute__((ext_vector_type(8))) _Float16 half8;
typedef __attribute__((ext_vector_type(4))) _Float16 half4;
typedef __attribute__((ext_vector_type(2))) _Float16 half2v;

__device__ __forceinline__ float wave_sum_all(float v) {
    #pragma unroll
    for (int off = 32; off > 0; off >>= 1) v += __shfl_xor(v, off, 64);
    return v;
}

__device__ __forceinline__ float dot8(const half8 a, const half8 b, float acc) {
#if __has_builtin(__builtin_amdgcn_fdot2)
    acc = __builtin_amdgcn_fdot2((half2v){a[0],a[1]}, (half2v){b[0],b[1]}, acc, false);
    acc = __builtin_amdgcn_fdot2((half2v){a[2],a[3]}, (half2v){b[2],b[3]}, acc, false);
    acc = __builtin_amdgcn_fdot2((half2v){a[4],a[5]}, (half2v){b[4],b[5]}, acc, false);
    acc = __builtin_amdgcn_fdot2((half2v){a[6],a[7]}, (half2v){b[6],b[7]}, acc, false);
    return acc;
#else
    #pragma unroll
    for (int e = 0; e < 8; ++e) acc += (float)a[e] * (float)b[e];
    return acc;
#endif
}

// softplus(z) = max(z,0) + log1p(exp(-|z|)), hardware exp/log.
__device__ __forceinline__ float softplus_fast(float z) {
    return fmaxf(z, 0.0f) + __logf(1.0f + __expf(-fabsf(z)));
}

// One WAVE per row (4 rows per 256-block) + fused triplet scatter.
__global__ __launch_bounds__(256) void prep_kernel(
    const float* __restrict__ x, const float* __restrict__ y,
    const float* __restrict__ norm_s,
    const int* __restrict__ trip, int* __restrict__ count,
    int2* __restrict__ slots,
    _Float16* __restrict__ xh, _Float16* __restrict__ yh,
    float2* __restrict__ sq)
{
    // ---- scatter: bucket this thread's triplet by i ----
    const int tid = blockIdx.x * 256 + threadIdx.x;
    if (tid < NTRIP) {
        const int i = trip[3*tid], j = trip[3*tid+1], k = trip[3*tid+2];
        const int c = atomicAdd(&count[i], 1);   // 200k atomics over 8192 addrs
        if (c < BINCAP) slots[((size_t)i << 6) + c] = (int2){j, k};
    }

    // ---- row prep: fp32 -> fp16, y normalization, rounded sq-norms ----
    const int row  = blockIdx.x * 4 + (threadIdx.x >> 6);
    const int lane = threadIdx.x & 63;
    const float4* xr = (const float4*)(x + (size_t)row * DDIM);
    const float4* yr = (const float4*)(y + (size_t)row * DDIM);
    const float4 x0 = xr[lane], x1 = xr[lane + 64];
    const float4 y0 = yr[lane], y1 = yr[lane + 64];

    float sy = y0.x*y0.x + y0.y*y0.y + y0.z*y0.z + y0.w*y0.w
             + y1.x*y1.x + y1.y*y1.y + y1.z*y1.z + y1.w*y1.w;
    sy = wave_sum_all(sy);
    const float scale = norm_s[0] / sqrtf(sy);

    const half4 hx0 = {(_Float16)x0.x, (_Float16)x0.y, (_Float16)x0.z, (_Float16)x0.w};
    const half4 hx1 = {(_Float16)x1.x, (_Float16)x1.y, (_Float16)x1.z, (_Float16)x1.w};
    const half4 hy0 = {(_Float16)(y0.x*scale), (_Float16)(y0.y*scale),
                       (_Float16)(y0.z*scale), (_Float16)(y0.w*scale)};
    const half4 hy1 = {(_Float16)(y1.x*scale), (_Float16)(y1.y*scale),
                       (_Float16)(y1.z*scale), (_Float16)(y1.w*scale)};

    // sq-norms of the ROUNDED values so i==j distances cancel before the clamp
    float sx = 0.f, sqy = 0.f;
    #pragma unroll
    for (int e = 0; e < 4; ++e) {
        sx  += (float)hx0[e]*(float)hx0[e] + (float)hx1[e]*(float)hx1[e];
        sqy += (float)hy0[e]*(float)hy0[e] + (float)hy1[e]*(float)hy1[e];
    }
    sx  = wave_sum_all(sx);
    sqy = wave_sum_all(sqy);

    ((half4*)(xh + (size_t)row * DDIM))[lane]      = hx0;
    ((half4*)(xh + (size_t)row * DDIM))[lane + 64] = hx1;
    ((half4*)(yh + (size_t)row * DDIM))[lane]      = hy0;
    ((half4*)(yh + (size_t)row * DDIM))[lane + 64] = hy1;
    if (lane == 0) sq[row] = (float2){sx, sqy};
}

// Grid-stride over (bin, chunk-of-16) work units. 4 groups of 16 lanes:
// g0:x_j g1:x_k g2:y_j g3:y_k; all 4 dots of a triplet reduce in one
// 4-level butterfly; transposed epilogue (img z in g0, txt z in g2).
// Last-finished block reduces all block partials into out[0] (no separate
// reduce dispatch, no contended float atomics).
__global__ __launch_bounds__(256) void trip_kernel(
    const _Float16* __restrict__ xh, const _Float16* __restrict__ yh,
    const float2* __restrict__ sq, const int* __restrict__ count,
    const int2* __restrict__ slots, float* __restrict__ bpart,
    int* __restrict__ done, float* __restrict__ out)
{
    const int tid    = threadIdx.x;
    const int lane   = tid & 63;
    const int wv     = tid >> 6;
    const int nwaves = gridDim.x * 4;

    const int  s     = lane & 15;          // slice within row
    const bool isK   = (lane & 16) != 0;   // groups 1,3 -> k-row
    const bool isTxt = (lane & 32) != 0;   // groups 2,3 -> y
    const _Float16* base = isTxt ? yh : xh;

    float acc = 0.0f;
    for (int chunk = blockIdx.x * 4 + wv; chunk < NCHUNKS; chunk += nwaves) {
        const int c   = chunk >> 13;          // chunk-major ordering
        const int bin = chunk & (NROWS - 1);  // == i

        int n = count[bin];
        n = __builtin_amdgcn_readfirstlane(n < BINCAP ? n : BINCAP);
        int m = n - c * CHUNK;
        if (m <= 0) continue;
        if (m > CHUNK) m = CHUNK;

        const half8* irow = ((const half8*)(base + (size_t)bin * DDIM)) + (s << 2);
        const half8 ci0 = irow[0], ci1 = irow[1], ci2 = irow[2], ci3 = irow[3];
        const float2 sqi = sq[bin];
        const float sq_self = isTxt ? sqi.y : sqi.x;
        const int2* bs = slots + ((size_t)bin << 6) + c * CHUNK;

        int t = 0;
        for (; t + 4 <= m; t += 4) {
            int jj[4], kk[4];
            #pragma unroll
            for (int u = 0; u < 4; ++u) {
                const int2 p = bs[t + u];
                jj[u] = __builtin_amdgcn_readfirstlane(p.x);
                kk[u] = __builtin_amdgcn_readfirstlane(p.y);
            }
            half8 rv[4][4];
            #pragma unroll
            for (int u = 0; u < 4; ++u) {
                const int r = isK ? kk[u] : jj[u];
                const half8* rp = ((const half8*)(base + (size_t)r * DDIM)) + (s << 2);
                rv[u][0] = rp[0]; rv[u][1] = rp[1]; rv[u][2] = rp[2]; rv[u][3] = rp[3];
            }
            float sq_r[4];
            #pragma unroll
            for (int u = 0; u < 4; ++u) {
                const float2 sqj = sq[jj[u]];
                const float2 sqk = sq[kk[u]];
                sq_r[u] = isTxt ? (isK ? sqk.y : sqj.y) : (isK ? sqk.x : sqj.x);
            }
            float dist[4];
            #pragma unroll
            for (int u = 0; u < 4; ++u) {
                float p = dot8(ci0, rv[u][0], 0.0f);
                p = dot8(ci1, rv[u][1], p);
                p = dot8(ci2, rv[u][2], p);
                p = dot8(ci3, rv[u][3], p);
                #pragma unroll
                for (int off = 1; off < 16; off <<= 1) p += __shfl_xor(p, off, 64);
                dist[u] = fmaxf(sq_self + sq_r[u] - 2.0f * p, 0.0f);
            }
            #pragma unroll
            for (int u = 0; u < 4; ++u) {
                const float z = dist[u] - __shfl_xor(dist[u], 16, 64);
                acc += isK ? 0.0f : softplus_fast(z);  // groups 0 (img), 2 (txt)
            }
        }
        for (; t < m; ++t) {  // tail, <=3 iterations
            const int2 p0 = bs[t];
            const int j0 = __builtin_amdgcn_readfirstlane(p0.x);
            const int k0 = __builtin_amdgcn_readfirstlane(p0.y);
            const int r = isK ? k0 : j0;
            const half8* rp = ((const half8*)(base + (size_t)r * DDIM)) + (s << 2);
            float p = dot8(ci0, rp[0], 0.0f);
            p = dot8(ci1, rp[1], p);
            p = dot8(ci2, rp[2], p);
            p = dot8(ci3, rp[3], p);
            #pragma unroll
            for (int off = 1; off < 16; off <<= 1) p += __shfl_xor(p, off, 64);
            const float2 sqj = sq[j0];
            const float2 sqk = sq[k0];
            const float sq_r = isTxt ? (isK ? sqk.y : sqj.y) : (isK ? sqk.x : sqj.x);
            const float dist = fmaxf(sq_self + sq_r - 2.0f * p, 0.0f);
            const float z = dist - __shfl_xor(dist, 16, 64);
            acc += isK ? 0.0f : softplus_fast(z);
        }
    }

    // ---- block partial (every block writes; no zeroing needed) ----
    acc = wave_sum_all(acc);
    __shared__ float red[4];
    __shared__ int slast;
    if (lane == 0) red[wv] = acc;
    __syncthreads();
    if (tid == 0) {
        const float bsum = red[0] + red[1] + red[2] + red[3];
        // device-scope release store: visible across XCDs before done++
        __hip_atomic_store(&bpart[blockIdx.x], bsum, __ATOMIC_RELEASE,
                           __HIP_MEMORY_SCOPE_AGENT);
        const int old = __hip_atomic_fetch_add(done, 1, __ATOMIC_ACQ_REL,
                                               __HIP_MEMORY_SCOPE_AGENT);
        slast = (old == (int)gridDim.x - 1);
    }
    __syncthreads();

    // ---- last block reduces all partials into out[0] ----
    if (slast) {
        float ssum = 0.0f;
        for (int b = tid; b < (int)gridDim.x; b += 256)
            ssum += __hip_atomic_load(&bpart[b], __ATOMIC_RELAXED,
                                      __HIP_MEMORY_SCOPE_AGENT);
        ssum = wave_sum_all(ssum);
        __shared__ float red2[4];
        if (lane == 0) red2[wv] = ssum;
        __syncthreads();
        if (tid == 0)
            out[0] = (red2[0] + red2[1] + red2[2] + red2[3])
                     * (1.0f / (16.0f * (float)NTRIP));
    }
}

extern "C" void kernel_launch(void* const* d_in, const int* in_sizes, int n_in,
                              void* d_out, int out_size, void* d_ws, size_t ws_size,
                              hipStream_t stream) {
    const float* x      = (const float*)d_in[0];
    const float* y      = (const float*)d_in[1];
    const float* norm_s = (const float*)d_in[2];
    const int*   trip   = (const int*)d_in[3];

    _Float16* xh    = (_Float16*)d_ws;                          // 8 MB
    _Float16* yh    = xh + (size_t)NROWS * DDIM;                // 8 MB
    float2*   sq    = (float2*)(yh + (size_t)NROWS * DDIM);     // 64 KB
    int*      count = (int*)(sq + NROWS);                       // 32 KB
    int*      done  = count + NROWS;                            // 1 int (+3 pad)
    float*    bpart = (float*)(done + 4);                       // TBLOCKS floats
    int2*     slots = (int2*)(bpart + TBLOCKS);                 // 4 MB (16B-aligned)

    // one DMA node zeroes count + done together
    hipMemsetAsync(count, 0, sizeof(int) * (NROWS + 4), stream);

    prep_kernel<<<NROWS / 4, 256, 0, stream>>>(x, y, norm_s, trip, count, slots,
                                               xh, yh, sq);
    trip_kernel<<<TBLOCKS, 256, 0, stream>>>(xh, yh, sq, count, slots, bpart,
                                             done, (float*)d_out);
}

// Round 10
// 144.556 us; speedup vs baseline: 3.6176x; 1.6561x over previous
//
#include <hip/hip_runtime.h>
#include <math.h>

#define NROWS 8192
#define DDIM  512
#define NTRIP 200000
#define CHUNK 16                  // triplets per work unit (balance quantum)
#define MAXCH 4                   // chunks per bin
#define BINCAP 64
#define NCHUNKS (NROWS * MAXCH)   // 32768
#define ROWU 128                  // uints per fp8 row (512 B)

typedef __attribute__((ext_vector_type(2))) float f32x2;

__device__ __forceinline__ float wave_sum_all(float v) {
    #pragma unroll
    for (int off = 32; off > 0; off >>= 1) v += __shfl_xor(v, off, 64);
    return v;
}

// 2 fp8 bytes -> 2 floats (hardware v_cvt_pk_f32_fp8). HI must be a
// compile-time constant (builtin requires constant integer selector).
template<bool HI>
__device__ __forceinline__ f32x2 cvt2(unsigned int u) {
    return __builtin_amdgcn_cvt_pk_f32_fp8((int)u, HI);
}
// 4 floats -> 4 fp8 bytes in one uint (hardware v_cvt_pk_fp8_f32)
__device__ __forceinline__ unsigned int pack4(float a, float b, float c, float d) {
    int v = __builtin_amdgcn_cvt_pk_fp8_f32(a, b, 0, false);
    v = __builtin_amdgcn_cvt_pk_fp8_f32(c, d, v, true);
    return (unsigned int)v;
}

// softplus(z) = max(z,0) + log1p(exp(-|z|)), hardware exp/log.
__device__ __forceinline__ float softplus_fast(float z) {
    return fmaxf(z, 0.0f) + __logf(1.0f + __expf(-fabsf(z)));
}

// dot of 32 fp8 elements (8 uints) against pre-converted ci[16] f32x2 slices
__device__ __forceinline__ float dot32(const uint4 ra, const uint4 rb,
                                       const f32x2* __restrict__ ci) {
    f32x2 a2;
    a2  = cvt2<false>(ra.x) * ci[0];
    a2  = cvt2<true >(ra.x) * ci[1]  + a2;
    a2  = cvt2<false>(ra.y) * ci[2]  + a2;
    a2  = cvt2<true >(ra.y) * ci[3]  + a2;
    a2  = cvt2<false>(ra.z) * ci[4]  + a2;
    a2  = cvt2<true >(ra.z) * ci[5]  + a2;
    a2  = cvt2<false>(ra.w) * ci[6]  + a2;
    a2  = cvt2<true >(ra.w) * ci[7]  + a2;
    a2  = cvt2<false>(rb.x) * ci[8]  + a2;
    a2  = cvt2<true >(rb.x) * ci[9]  + a2;
    a2  = cvt2<false>(rb.y) * ci[10] + a2;
    a2  = cvt2<true >(rb.y) * ci[11] + a2;
    a2  = cvt2<false>(rb.z) * ci[12] + a2;
    a2  = cvt2<true >(rb.z) * ci[13] + a2;
    a2  = cvt2<false>(rb.w) * ci[14] + a2;
    a2  = cvt2<true >(rb.w) * ci[15] + a2;
    return a2.x + a2.y;
}

// One WAVE per row (4 rows per 256-block) + fused triplet scatter.
// Stores fp8 x and fp8 (32*normalized y); sq-norms computed from the
// ROUNDED values (y descaled by /1024) so i==j distances cancel pre-clamp.
__global__ __launch_bounds__(256) void prep_kernel(
    const float* __restrict__ x, const float* __restrict__ y,
    const float* __restrict__ norm_s,
    const int* __restrict__ trip, int* __restrict__ count,
    int2* __restrict__ slots,
    unsigned int* __restrict__ xq, unsigned int* __restrict__ yq,
    float2* __restrict__ sq)
{
    // ---- scatter: bucket this thread's triplet by i ----
    const int tid = blockIdx.x * 256 + threadIdx.x;
    if (tid < NTRIP) {
        const int i = trip[3*tid], j = trip[3*tid+1], k = trip[3*tid+2];
        const int c = atomicAdd(&count[i], 1);   // 200k atomics over 8192 addrs
        if (c < BINCAP) slots[((size_t)i << 6) + c] = (int2){j, k};
    }

    // ---- row prep ----
    const int row  = blockIdx.x * 4 + (threadIdx.x >> 6);
    const int lane = threadIdx.x & 63;
    const float4* xr = (const float4*)(x + (size_t)row * DDIM);
    const float4* yr = (const float4*)(y + (size_t)row * DDIM);
    const float4 x0 = xr[lane], x1 = xr[lane + 64];
    const float4 y0 = yr[lane], y1 = yr[lane + 64];

    // y norm from ORIGINAL fp32 values (matches reference)
    float sy = y0.x*y0.x + y0.y*y0.y + y0.z*y0.z + y0.w*y0.w
             + y1.x*y1.x + y1.y*y1.y + y1.z*y1.z + y1.w*y1.w;
    sy = wave_sum_all(sy);
    // extra *32 keeps fp8 y values in normal range (descale dots by 1/1024)
    const float scale = norm_s[0] * 32.0f / sqrtf(sy);

    const unsigned int ux0 = pack4(x0.x, x0.y, x0.z, x0.w);
    const unsigned int ux1 = pack4(x1.x, x1.y, x1.z, x1.w);
    const unsigned int uy0 = pack4(y0.x*scale, y0.y*scale, y0.z*scale, y0.w*scale);
    const unsigned int uy1 = pack4(y1.x*scale, y1.y*scale, y1.z*scale, y1.w*scale);

    // sums of squares of the ROUNDED values
    f32x2 sx2 = {0.f, 0.f}, sy2 = {0.f, 0.f};
    {
        f32x2 a;
        a = cvt2<false>(ux0); sx2 = a*a + sx2;
        a = cvt2<true >(ux0); sx2 = a*a + sx2;
        a = cvt2<false>(ux1); sx2 = a*a + sx2;
        a = cvt2<true >(ux1); sx2 = a*a + sx2;
        a = cvt2<false>(uy0); sy2 = a*a + sy2;
        a = cvt2<true >(uy0); sy2 = a*a + sy2;
        a = cvt2<false>(uy1); sy2 = a*a + sy2;
        a = cvt2<true >(uy1); sy2 = a*a + sy2;
    }
    float sx  = wave_sum_all(sx2.x + sx2.y);
    float sqy = wave_sum_all(sy2.x + sy2.y) * (1.0f / 1024.0f);

    ((uint2*)(xq + (size_t)row * ROWU))[lane] = (uint2){ux0, ux1};
    ((uint2*)(yq + (size_t)row * ROWU))[lane] = (uint2){uy0, uy1};
    if (lane == 0) sq[row] = (float2){sx, sqy};
}

// One wave per (bin, chunk-of-16), one-shot (R6 structure: best latency
// hiding). 4 groups of 16 lanes: g0:x_j g1:x_k g2:y_j g3:y_k; lane slice =
// 32 fp8 elements (2 dwordx4 loads/row). All 4 dots reduce in one 4-level
// butterfly; transposed epilogue. Block partial -> bpart[block] (no atomics).
__global__ __launch_bounds__(256) void trip_kernel(
    const unsigned int* __restrict__ xq, const unsigned int* __restrict__ yq,
    const float2* __restrict__ sq, const int* __restrict__ count,
    const int2* __restrict__ slots, float* __restrict__ bpart)
{
    const int tid  = threadIdx.x;
    const int lane = tid & 63;
    const int wv   = tid >> 6;
    const int chunk = blockIdx.x * 4 + wv;
    const int c    = chunk >> 13;          // chunk-major
    const int bin  = chunk & (NROWS - 1);  // == i

    float acc = 0.0f;
    int n = count[bin];
    n = __builtin_amdgcn_readfirstlane(n < BINCAP ? n : BINCAP);
    int m = n - c * CHUNK;
    if (m > 0) {
        if (m > CHUNK) m = CHUNK;

        const int  s     = lane & 15;
        const bool isK   = (lane & 16) != 0;
        const bool isTxt = (lane & 32) != 0;
        const unsigned int* base = isTxt ? yq : xq;
        const float dscale = isTxt ? (1.0f / 1024.0f) : 1.0f;

        // i-row slice: load 32 B, convert once to 32 floats (16 f32x2)
        const uint4* irow = ((const uint4*)(base + (size_t)bin * ROWU)) + (s << 1);
        const uint4 qa = irow[0], qb = irow[1];
        f32x2 ci[16];
        ci[0]=cvt2<false>(qa.x);  ci[1]=cvt2<true>(qa.x);
        ci[2]=cvt2<false>(qa.y);  ci[3]=cvt2<true>(qa.y);
        ci[4]=cvt2<false>(qa.z);  ci[5]=cvt2<true>(qa.z);
        ci[6]=cvt2<false>(qa.w);  ci[7]=cvt2<true>(qa.w);
        ci[8]=cvt2<false>(qb.x);  ci[9]=cvt2<true>(qb.x);
        ci[10]=cvt2<false>(qb.y); ci[11]=cvt2<true>(qb.y);
        ci[12]=cvt2<false>(qb.z); ci[13]=cvt2<true>(qb.z);
        ci[14]=cvt2<false>(qb.w); ci[15]=cvt2<true>(qb.w);

        const float2 sqi = sq[bin];
        const float sq_self = isTxt ? sqi.y : sqi.x;
        const int2* bs = slots + ((size_t)bin << 6) + c * CHUNK;

        int t = 0;
        for (; t + 4 <= m; t += 4) {
            int jj[4], kk[4];
            #pragma unroll
            for (int u = 0; u < 4; ++u) {
                const int2 p = bs[t + u];
                jj[u] = __builtin_amdgcn_readfirstlane(p.x);
                kk[u] = __builtin_amdgcn_readfirstlane(p.y);
            }
            uint4 ra[4], rb[4];
            #pragma unroll
            for (int u = 0; u < 4; ++u) {
                const int r = isK ? kk[u] : jj[u];
                const uint4* rp = ((const uint4*)(base + (size_t)r * ROWU)) + (s << 1);
                ra[u] = rp[0]; rb[u] = rp[1];
            }
            float sq_r[4];
            #pragma unroll
            for (int u = 0; u < 4; ++u) {
                const float2 sqj = sq[jj[u]];
                const float2 sqk = sq[kk[u]];
                sq_r[u] = isTxt ? (isK ? sqk.y : sqj.y) : (isK ? sqk.x : sqj.x);
            }
            float dist[4];
            #pragma unroll
            for (int u = 0; u < 4; ++u) {
                float p = dot32(ra[u], rb[u], ci);
                #pragma unroll
                for (int off = 1; off < 16; off <<= 1) p += __shfl_xor(p, off, 64);
                dist[u] = fmaxf(sq_self + sq_r[u] - 2.0f * p * dscale, 0.0f);
            }
            #pragma unroll
            for (int u = 0; u < 4; ++u) {
                const float z = dist[u] - __shfl_xor(dist[u], 16, 64);
                acc += isK ? 0.0f : softplus_fast(z);  // groups 0 (img), 2 (txt)
            }
        }
        for (; t < m; ++t) {  // tail, <=3 iterations
            const int2 p0 = bs[t];
            const int j0 = __builtin_amdgcn_readfirstlane(p0.x);
            const int k0 = __builtin_amdgcn_readfirstlane(p0.y);
            const int r = isK ? k0 : j0;
            const uint4* rp = ((const uint4*)(base + (size_t)r * ROWU)) + (s << 1);
            float p = dot32(rp[0], rp[1], ci);
            #pragma unroll
            for (int off = 1; off < 16; off <<= 1) p += __shfl_xor(p, off, 64);
            const float2 sqj = sq[j0];
            const float2 sqk = sq[k0];
            const float sq_r = isTxt ? (isK ? sqk.y : sqj.y) : (isK ? sqk.x : sqj.x);
            const float dist = fmaxf(sq_self + sq_r - 2.0f * p * dscale, 0.0f);
            const float z = dist - __shfl_xor(dist, 16, 64);
            acc += isK ? 0.0f : softplus_fast(z);
        }
    }

    // block partial: EVERY block writes its slot (no zeroing, no atomics)
    acc = wave_sum_all(acc);
    __shared__ float red[4];
    if (lane == 0) red[wv] = acc;
    __syncthreads();
    if (tid == 0) bpart[blockIdx.x] = red[0] + red[1] + red[2] + red[3];
}

// Single block reduces the 8192 block partials; plain store to out[0].
__global__ __launch_bounds__(256) void reduce_kernel(
    const float* __restrict__ bpart, float* __restrict__ out)
{
    float s = 0.0f;
    for (int i = threadIdx.x; i < NCHUNKS / 4; i += 256) s += bpart[i];
    s = wave_sum_all(s);
    __shared__ float red[4];
    const int wv = threadIdx.x >> 6, lane = threadIdx.x & 63;
    if (lane == 0) red[wv] = s;
    __syncthreads();
    if (threadIdx.x == 0)
        out[0] = (red[0] + red[1] + red[2] + red[3])
                 * (1.0f / (16.0f * (float)NTRIP));
}

extern "C" void kernel_launch(void* const* d_in, const int* in_sizes, int n_in,
                              void* d_out, int out_size, void* d_ws, size_t ws_size,
                              hipStream_t stream) {
    const float* x      = (const float*)d_in[0];
    const float* y      = (const float*)d_in[1];
    const float* norm_s = (const float*)d_in[2];
    const int*   trip   = (const int*)d_in[3];

    unsigned int* xq    = (unsigned int*)d_ws;                  // 4 MB
    unsigned int* yq    = xq + (size_t)NROWS * ROWU;            // 4 MB
    float2*       sq    = (float2*)(yq + (size_t)NROWS * ROWU); // 64 KB
    int*          count = (int*)(sq + NROWS);                   // 32 KB
    float*        bpart = (float*)(count + NROWS);              // 32 KB
    int2*         slots = (int2*)(bpart + NCHUNKS / 4);         // 4 MB

    (void)hipMemsetAsync(count, 0, sizeof(int) * NROWS, stream);
    prep_kernel<<<NROWS / 4, 256, 0, stream>>>(x, y, norm_s, trip, count, slots,
                                               xq, yq, sq);
    trip_kernel<<<NCHUNKS / 4, 256, 0, stream>>>(xq, yq, sq, count, slots, bpart);
    reduce_kernel<<<1, 256, 0, stream>>>(bpart, (float*)d_out);
}